// Round 8
// baseline (248.345 us; speedup 1.0000x reference)
//
#include <hip/hip_runtime.h>
#include <math.h>

// Problem constants (from setup_inputs): x is (B=32, C=3, H=512, W=512) fp32.
constexpr int B = 32;
constexpr int C = 3;
constexpr int H = 512;
constexpr int W = 512;
constexpr int HW = H * W;

// ---------------------------------------------------------------------------
// Single-kernel affine warp, bilinear, zero padding.
//
// R6 = baseline body (63.6 us: per-tap predicated float2 gathers, plain
// stores, no launch-bounds cap) + ONE change: work-conserving block mapping.
//
//   bid = blockIdx.x (1D, 8192)
//   batch = bid & 31   -> batches interleaved fastest (mixes heavy/light
//                         batches, per-batch work ~ l1*l2 varies ~4x)
//   slot  = bid >> 5   -> block covers rows {slot, slot+256} = Y and Y+1:
//                         valid region is a CENTERED parallelogram, width
//                         w(Y) triangular -> w(Y)+w(Y+1) ~ constant, so
//                         every block carries ~mean load.
//
// Evidence trail:
//  - dur pinned at 63.6-64.2 across ALL memory-path variants; no pipe >43%;
//    Occupancy 39% despite VGPR=48 allowing 8 waves/SIMD -> CU starvation
//    from heavy-center-row block bursts (tail), not pipe saturation.
//  - R1/R2: branchless gathers +15us -> keep predication.
//  - R3: XCD swizzle halves FETCH, +3.4us -> not HBM-BW-bound; reverted.
//  - R4/R5: MLP hoist/fence neutral (compiler re-interleaves consumes);
//    VGPR never rose -> per-wave MLP untestable at source level; reverted.
//
// Affine reduction: overall = fw^-1 * diag(1/l1,1/l2,1) * fw; translation
// cancels, leaving a pure 2x2 linear map (fp64 by thread 0, LDS broadcast).
// ---------------------------------------------------------------------------
__global__ __launch_bounds__(256)
void warp_kernel(const float* __restrict__ x,
                 const float* __restrict__ thetas,
                 const float* __restrict__ l1s,
                 const float* __restrict__ l2s,
                 float* __restrict__ out) {
    const int bid  = blockIdx.x;          // 0..8191
    const int b    = bid & 31;            // batch, fastest-varying
    const int slot = bid >> 5;            // 0..255 row-slot

    __shared__ float sc[4];
    if (threadIdx.x == 0) {
        double th = -(double)thetas[b];
        double c = cos(th), s = sin(th);
        double a = 1.0 / (double)l1s[b];
        double d = 1.0 / (double)l2s[b];
        sc[0] = (float)(a * c * c + d * s * s);
        sc[1] = (float)(c * s * (d - a));
        sc[2] = sc[1];
        sc[3] = (float)(a * s * s + d * c * c);
    }
    __syncthreads();
    const float t00 = sc[0], t01 = sc[1], t10 = sc[2], t11 = sc[3];

    const int tid   = threadIdx.x;
    const int lane  = tid & 63;
    const int wv    = tid >> 6;                 // wave id 0..3
    // waves 0,1 -> row slot (top half), waves 2,3 -> row slot+256 (bottom):
    // pairs a light edge-row with a heavy center-row in the same block.
    const int h     = slot | ((wv >> 1) << 8);
    const int wbase = (wv & 1) << 8;            // 0 or 256

    const float Y = ((float)h + 0.5f) * (2.0f / (float)H) - 1.0f;

    // ---- geometry for the 4 pixels ----
    int   row0[4], row1[4];
    bool  xeq[4], vx0[4], vx1[4], pr0[4], pr1[4];
    float w00[4], w01[4], w10[4], w11[4];
    bool any_valid = false;

    #pragma unroll
    for (int j = 0; j < 4; ++j) {
        const int w = wbase + (j << 6) + lane;
        const float X = ((float)w + 0.5f) * (2.0f / (float)W) - 1.0f;
        const float gx = (t00 * X + t01 * Y + 1.0f) * ((float)W * 0.5f) - 0.5f;
        const float gy = (t10 * X + t11 * Y + 1.0f) * ((float)H * 0.5f) - 0.5f;

        const float x0f = floorf(gx), y0f = floorf(gy);
        const float wx1 = gx - x0f, wx0 = 1.0f - wx1;
        const float wy1 = gy - y0f, wy0 = 1.0f - wy1;

        const int x0 = (int)x0f, y0 = (int)y0f;
        const int x1 = x0 + 1,  y1 = y0 + 1;

        vx0[j] = ((unsigned)x0 < (unsigned)W);
        vx1[j] = ((unsigned)x1 < (unsigned)W);
        const bool vy0 = ((unsigned)y0 < (unsigned)H);
        const bool vy1 = ((unsigned)y1 < (unsigned)H);

        const int xbj = min(max(x0, 0), W - 2);   // float2 base, in-bounds
        xeq[j] = (x0 == xbj);
        const bool anyx = vx0[j] || vx1[j];
        pr0[j] = vy0 && anyx;
        pr1[j] = vy1 && anyx;
        any_valid = any_valid || pr0[j] || pr1[j];

        row0[j] = min(max(y0, 0), H - 1) * W + xbj;
        row1[j] = min(max(y1, 0), H - 1) * W + xbj;

        w00[j] = wy0 * wx0; w01[j] = wy0 * wx1;
        w10[j] = wy1 * wx0; w11[j] = wy1 * wx1;
    }

    float r[C][4];
    #pragma unroll
    for (int ch = 0; ch < C; ++ch)
        #pragma unroll
        for (int j = 0; j < 4; ++j) r[ch][j] = 0.0f;

    if (any_valid) {
        const float* __restrict__ base = x + (size_t)b * C * HW;
        #pragma unroll
        for (int j = 0; j < 4; ++j) {
            #pragma unroll
            for (int ch = 0; ch < C; ++ch) {
                const float* __restrict__ p = base + ch * HW;
                float2 a0 = make_float2(0.0f, 0.0f);
                float2 a1 = make_float2(0.0f, 0.0f);
                if (pr0[j]) a0 = *reinterpret_cast<const float2*>(p + row0[j]);
                if (pr1[j]) a1 = *reinterpret_cast<const float2*>(p + row1[j]);
                const float v00 = vx0[j] ? (xeq[j] ? a0.x : a0.y) : 0.0f;
                const float v01 = vx1[j] ? (xeq[j] ? a0.y : a0.x) : 0.0f;
                const float v10 = vx0[j] ? (xeq[j] ? a1.x : a1.y) : 0.0f;
                const float v11 = vx1[j] ? (xeq[j] ? a1.y : a1.x) : 0.0f;
                r[ch][j] = v00 * w00[j] + v01 * w01[j] + v10 * w10[j] + v11 * w11[j];
            }
        }
    }

    const size_t obase = (size_t)b * C * HW + (size_t)h * W + (size_t)wbase + lane;
    #pragma unroll
    for (int ch = 0; ch < C; ++ch) {
        #pragma unroll
        for (int j = 0; j < 4; ++j) {
            out[obase + (size_t)ch * HW + (j << 6)] = r[ch][j];
        }
    }
}

extern "C" void kernel_launch(void* const* d_in, const int* in_sizes, int n_in,
                              void* d_out, int out_size, void* d_ws, size_t ws_size,
                              hipStream_t stream) {
    const float* x      = (const float*)d_in[0];
    const float* thetas = (const float*)d_in[1];
    const float* l1s    = (const float*)d_in[2];
    const float* l2s    = (const float*)d_in[3];
    float* out          = (float*)d_out;

    warp_kernel<<<dim3((H / 2) * B), 256, 0, stream>>>(x, thetas, l1s, l2s, out);
}

// Round 9
// 190.425 us; speedup vs baseline: 1.3042x; 1.3042x over previous
//
#include <hip/hip_runtime.h>
#include <math.h>

// Problem constants (from setup_inputs): x is (B=32, C=3, H=512, W=512) fp32.
constexpr int B = 32;
constexpr int C = 3;
constexpr int H = 512;
constexpr int W = 512;
constexpr int HW = H * W;

// ---------------------------------------------------------------------------
// Single-kernel affine warp, bilinear, zero padding.
//
// R7 = ONE PIXEL PER THREAD (was 4). Same per-pixel arithmetic, same
// predicated float2 gathers, same batch-major/row-major block ordering as
// the 63.6us baseline. Block = 256 consecutive pixels of one row;
// grid = (H*2, B), bx fastest -> adjacent blocks cover adjacent row
// segments of the same batch (baseline's L2-favorable order).
//
// Why: 7 runs show time = loads x latency / (waves x inflight_per_wave).
//  - R4/R5: per-wave MLP is compiler-pinned at ~6 regardless of source
//    structure (hoist + memory fence both re-interleaved; VGPR never rose).
//  - R6: batch-interleaved mapping -> all gathers LLC-latency -> dur
//    EXACTLY doubled with all rate counters halved => latency-bound, and
//    load balance is irrelevant (uniform slowdown, no tail).
//  - R3: L2-affinity swizzle couldn't beat baseline's latency mix.
//  => only remaining lever: MORE WAVES. 1 px/thread turns the per-thread
//  serial chain of 4 latency exposures into 1 and quadruples wave count;
//  chip-level in-flight loads (waves x ~6) rise ~2-3x.
//
// Affine reduction: overall = fw^-1 * diag(1/l1,1/l2,1) * fw; translation
// cancels, leaving a pure 2x2 linear map (fp64 by thread 0, LDS broadcast).
// ---------------------------------------------------------------------------
__global__ __launch_bounds__(256)
void warp_kernel(const float* __restrict__ x,
                 const float* __restrict__ thetas,
                 const float* __restrict__ l1s,
                 const float* __restrict__ l2s,
                 float* __restrict__ out) {
    const int b = blockIdx.y;

    __shared__ float sc[4];
    if (threadIdx.x == 0) {
        double th = -(double)thetas[b];
        double c = cos(th), s = sin(th);
        double a = 1.0 / (double)l1s[b];
        double d = 1.0 / (double)l2s[b];
        sc[0] = (float)(a * c * c + d * s * s);
        sc[1] = (float)(c * s * (d - a));
        sc[2] = sc[1];
        sc[3] = (float)(a * s * s + d * c * c);
    }
    __syncthreads();
    const float t00 = sc[0], t01 = sc[1], t10 = sc[2], t11 = sc[3];

    // One pixel per thread: row h, column w.
    const int h = blockIdx.x >> 1;
    const int w = ((blockIdx.x & 1) << 8) | threadIdx.x;

    const float Y = ((float)h + 0.5f) * (2.0f / (float)H) - 1.0f;
    const float X = ((float)w + 0.5f) * (2.0f / (float)W) - 1.0f;
    const float gx = (t00 * X + t01 * Y + 1.0f) * ((float)W * 0.5f) - 0.5f;
    const float gy = (t10 * X + t11 * Y + 1.0f) * ((float)H * 0.5f) - 0.5f;

    const float x0f = floorf(gx), y0f = floorf(gy);
    const float wx1 = gx - x0f, wx0 = 1.0f - wx1;
    const float wy1 = gy - y0f, wy0 = 1.0f - wy1;

    const int x0 = (int)x0f, y0 = (int)y0f;
    const int x1 = x0 + 1,  y1 = y0 + 1;

    const bool vx0 = ((unsigned)x0 < (unsigned)W);
    const bool vx1 = ((unsigned)x1 < (unsigned)W);
    const bool vy0 = ((unsigned)y0 < (unsigned)H);
    const bool vy1 = ((unsigned)y1 < (unsigned)H);

    const int xb  = min(max(x0, 0), W - 2);   // float2 base, always in-bounds
    const bool xeq = (x0 == xb);
    const bool anyx = vx0 || vx1;
    const bool pr0 = vy0 && anyx;
    const bool pr1 = vy1 && anyx;

    const int row0 = min(max(y0, 0), H - 1) * W + xb;
    const int row1 = min(max(y1, 0), H - 1) * W + xb;

    const float w00 = wy0 * wx0, w01 = wy0 * wx1;
    const float w10 = wy1 * wx0, w11 = wy1 * wx1;

    float r[C];
    #pragma unroll
    for (int ch = 0; ch < C; ++ch) r[ch] = 0.0f;

    if (pr0 || pr1) {
        const float* __restrict__ base = x + (size_t)b * C * HW;

        float2 a0[C], a1[C];
        #pragma unroll
        for (int ch = 0; ch < C; ++ch) {
            a0[ch] = make_float2(0.0f, 0.0f);
            a1[ch] = make_float2(0.0f, 0.0f);
            if (pr0) a0[ch] = *reinterpret_cast<const float2*>(base + ch * HW + row0);
            if (pr1) a1[ch] = *reinterpret_cast<const float2*>(base + ch * HW + row1);
        }

        #pragma unroll
        for (int ch = 0; ch < C; ++ch) {
            const float v00 = vx0 ? (xeq ? a0[ch].x : a0[ch].y) : 0.0f;
            const float v01 = vx1 ? (xeq ? a0[ch].y : a0[ch].x) : 0.0f;
            const float v10 = vx0 ? (xeq ? a1[ch].x : a1[ch].y) : 0.0f;
            const float v11 = vx1 ? (xeq ? a1[ch].y : a1[ch].x) : 0.0f;
            r[ch] = v00 * w00 + v01 * w01 + v10 * w10 + v11 * w11;
        }
    }

    const size_t obase = (size_t)b * C * HW + (size_t)h * W + w;
    #pragma unroll
    for (int ch = 0; ch < C; ++ch) {
        out[obase + (size_t)ch * HW] = r[ch];
    }
}

extern "C" void kernel_launch(void* const* d_in, const int* in_sizes, int n_in,
                              void* d_out, int out_size, void* d_ws, size_t ws_size,
                              hipStream_t stream) {
    const float* x      = (const float*)d_in[0];
    const float* thetas = (const float*)d_in[1];
    const float* l1s    = (const float*)d_in[2];
    const float* l2s    = (const float*)d_in[3];
    float* out          = (float*)d_out;

    warp_kernel<<<dim3(H * 2, B), 256, 0, stream>>>(x, thetas, l1s, l2s, out);
}

// Round 10
// 190.314 us; speedup vs baseline: 1.3049x; 1.0006x over previous
//
#include <hip/hip_runtime.h>
#include <math.h>

// Problem constants (from setup_inputs): x is (B=32, C=3, H=512, W=512) fp32.
constexpr int B = 32;
constexpr int C = 3;
constexpr int H = 512;
constexpr int W = 512;
constexpr int HW = H * W;

// ---------------------------------------------------------------------------
// Single-kernel affine warp, bilinear, zero padding.
//
// R8 = R7 (1 px/thread, grid (H*2,B), batch-major/row-major order) + ONE
// change: wave-uniform interior fast path.
//   __all(lanes interior) -> 6 UNPREDICATED float2 loads, no exec-mask
//   toggles, no v_cndmask selects, straight FMAs. Edge/exterior waves take
//   the original predicated slow path.
//
// Evidence trail (dur pinned 63.6-67 across everything):
//  - R1/R2: +2x requests = +15us -> request count is the one lever that
//    moved time. Keep predication of truly-OOB loads.
//  - R3: L2-affinity halves FETCH, dur unchanged -> not DRAM-BW-bound.
//  - R4/R5: per-wave MLP pinned by compiler; untestable -> reverted.
//  - R6: 2x latency -> exactly 2x dur (latency-bound behavior).
//  - R7: 2x waves, 4x shorter chains -> dur UNCHANGED (occupancy 39->68).
//  => concurrency-insensitive, latency/request-cost-sensitive: a
//  per-request TA/TCP cost invariant to waves. This round removes the
//  per-request exec/select overhead in the interior to test how much of
//  the fixed cost is issue-side vs hardware-pipe-side.
//
// Affine reduction: overall = fw^-1 * diag(1/l1,1/l2,1) * fw; translation
// cancels, leaving a pure 2x2 linear map (fp64 by thread 0, LDS broadcast).
// ---------------------------------------------------------------------------
__global__ __launch_bounds__(256)
void warp_kernel(const float* __restrict__ x,
                 const float* __restrict__ thetas,
                 const float* __restrict__ l1s,
                 const float* __restrict__ l2s,
                 float* __restrict__ out) {
    const int b = blockIdx.y;

    __shared__ float sc[4];
    if (threadIdx.x == 0) {
        double th = -(double)thetas[b];
        double c = cos(th), s = sin(th);
        double a = 1.0 / (double)l1s[b];
        double d = 1.0 / (double)l2s[b];
        sc[0] = (float)(a * c * c + d * s * s);
        sc[1] = (float)(c * s * (d - a));
        sc[2] = sc[1];
        sc[3] = (float)(a * s * s + d * c * c);
    }
    __syncthreads();
    const float t00 = sc[0], t01 = sc[1], t10 = sc[2], t11 = sc[3];

    // One pixel per thread: row h, column w.
    const int h = blockIdx.x >> 1;
    const int w = ((blockIdx.x & 1) << 8) | threadIdx.x;

    const float Y = ((float)h + 0.5f) * (2.0f / (float)H) - 1.0f;
    const float X = ((float)w + 0.5f) * (2.0f / (float)W) - 1.0f;
    const float gx = (t00 * X + t01 * Y + 1.0f) * ((float)W * 0.5f) - 0.5f;
    const float gy = (t10 * X + t11 * Y + 1.0f) * ((float)H * 0.5f) - 0.5f;

    const float x0f = floorf(gx), y0f = floorf(gy);
    const float wx1 = gx - x0f, wx0 = 1.0f - wx1;
    const float wy1 = gy - y0f, wy0 = 1.0f - wy1;

    const int x0 = (int)x0f, y0 = (int)y0f;
    const int x1 = x0 + 1,  y1 = y0 + 1;

    const float w00 = wy0 * wx0, w01 = wy0 * wx1;
    const float w10 = wy1 * wx0, w11 = wy1 * wx1;

    float r[C];
    #pragma unroll
    for (int ch = 0; ch < C; ++ch) r[ch] = 0.0f;

    const float* __restrict__ base = x + (size_t)b * C * HW;

    // Interior: the whole 2x2 tap window is in-bounds -> no masking at all.
    const bool interior = ((unsigned)x0 < (unsigned)(W - 1)) &&
                          ((unsigned)y0 < (unsigned)(H - 1));

    if (__all(interior)) {
        // ---- FAST PATH (wave-uniform): unpredicated loads, no selects ----
        const int row0 = y0 * W + x0;
        const int row1 = row0 + W;
        float2 a0[C], a1[C];
        #pragma unroll
        for (int ch = 0; ch < C; ++ch) {
            a0[ch] = *reinterpret_cast<const float2*>(base + ch * HW + row0);
            a1[ch] = *reinterpret_cast<const float2*>(base + ch * HW + row1);
        }
        #pragma unroll
        for (int ch = 0; ch < C; ++ch) {
            r[ch] = a0[ch].x * w00 + a0[ch].y * w01 +
                    a1[ch].x * w10 + a1[ch].y * w11;
        }
    } else {
        // ---- SLOW PATH: per-tap predication (edge / exterior waves) ----
        const bool vx0 = ((unsigned)x0 < (unsigned)W);
        const bool vx1 = ((unsigned)x1 < (unsigned)W);
        const bool vy0 = ((unsigned)y0 < (unsigned)H);
        const bool vy1 = ((unsigned)y1 < (unsigned)H);

        const int xb  = min(max(x0, 0), W - 2);   // float2 base, in-bounds
        const bool xeq = (x0 == xb);
        const bool anyx = vx0 || vx1;
        const bool pr0 = vy0 && anyx;
        const bool pr1 = vy1 && anyx;

        const int row0 = min(max(y0, 0), H - 1) * W + xb;
        const int row1 = min(max(y1, 0), H - 1) * W + xb;

        if (pr0 || pr1) {
            float2 a0[C], a1[C];
            #pragma unroll
            for (int ch = 0; ch < C; ++ch) {
                a0[ch] = make_float2(0.0f, 0.0f);
                a1[ch] = make_float2(0.0f, 0.0f);
                if (pr0) a0[ch] = *reinterpret_cast<const float2*>(base + ch * HW + row0);
                if (pr1) a1[ch] = *reinterpret_cast<const float2*>(base + ch * HW + row1);
            }
            #pragma unroll
            for (int ch = 0; ch < C; ++ch) {
                const float v00 = vx0 ? (xeq ? a0[ch].x : a0[ch].y) : 0.0f;
                const float v01 = vx1 ? (xeq ? a0[ch].y : a0[ch].x) : 0.0f;
                const float v10 = vx0 ? (xeq ? a1[ch].x : a1[ch].y) : 0.0f;
                const float v11 = vx1 ? (xeq ? a1[ch].y : a1[ch].x) : 0.0f;
                r[ch] = v00 * w00 + v01 * w01 + v10 * w10 + v11 * w11;
            }
        }
    }

    const size_t obase = (size_t)b * C * HW + (size_t)h * W + w;
    #pragma unroll
    for (int ch = 0; ch < C; ++ch) {
        out[obase + (size_t)ch * HW] = r[ch];
    }
}

extern "C" void kernel_launch(void* const* d_in, const int* in_sizes, int n_in,
                              void* d_out, int out_size, void* d_ws, size_t ws_size,
                              hipStream_t stream) {
    const float* x      = (const float*)d_in[0];
    const float* thetas = (const float*)d_in[1];
    const float* l1s    = (const float*)d_in[2];
    const float* l2s    = (const float*)d_in[3];
    float* out          = (float*)d_out;

    warp_kernel<<<dim3(H * 2, B), 256, 0, stream>>>(x, thetas, l1s, l2s, out);
}